// Round 1
// 226.223 us; speedup vs baseline: 1.1662x; 1.1662x over previous
//
#include <hip/hip_runtime.h>
#include <math.h>

#define BB 16
#define QQ 900
#define CC 91
#define TT 100
#define BT (BB * TT)        // 1600
#define NTHREADS 256
#define TILE 15             // query rows per cost block (900 % 15 == 0)
#define NBLK_PER_IMG (QQ / TILE)   // 60
#define NSLOT 15            // ceil(900/64) row slots per lane
#define WSCOLS 128          // u64 workspace slots per image

__device__ __forceinline__ unsigned ordkey(float f) {
    unsigned u = __float_as_uint(f);
    return (u & 0x80000000u) ? ~u : (u | 0x80000000u);
}

__device__ __forceinline__ unsigned long long u64min(unsigned long long a, unsigned long long b) {
    return a < b ? a : b;
}

// pack (key,row,col) -> u64; lexicographic == numpy flat-index argmin order
__device__ __forceinline__ unsigned long long packkrc(unsigned key, int row, int col) {
    return ((unsigned long long)key << 21) | ((unsigned long long)row << 11) | (unsigned)col;
}

// ---------------------------------------------------------------------------
// Kernel 1: cost[b,q,j], tiled 15 rows/block with LDS-staged targets.
// Numerics are the EXACT expression tree of the verified kernel (expf, exact
// divides, same association) so cost bits and matcher tie-breaks are unchanged.
// Fused: per-block column minima of the matcher sub-block (cols 0..99),
// atomicMin'd into a packed-u64 workspace -> greedy phase 1 disappears.
// ---------------------------------------------------------------------------
__global__ __launch_bounds__(NTHREADS) void cost_kernel(
    const float* __restrict__ logits,
    const float* __restrict__ pred,
    const int*   __restrict__ tlab,
    const float* __restrict__ tbox,
    float*       __restrict__ cost,
    unsigned long long* __restrict__ colmin)
{
    const int b  = blockIdx.x / NBLK_PER_IMG;
    const int tb = blockIdx.x % NBLK_PER_IMG;
    const int r0 = tb * TILE;                 // first query row of this tile

    __shared__ float s_tx[BT], s_ty[BT], s_tz[BT], s_tw[BT];  // SoA: conflict-free b32 reads
    __shared__ int   s_lab[BT];
    __shared__ float s_sig[TILE][CC];
    __shared__ float s_row[TILE][8];          // px,py,pz,pw,x0,y0,x1,y1
    __shared__ float s_cmin[TILE][TT];        // matcher sub-block staging

    // stage targets (coalesced float4 global load -> SoA LDS)
    for (int j = threadIdx.x; j < BT; j += NTHREADS) {
        float4 t = *(const float4*)(tbox + (size_t)j * 4);
        s_tx[j] = t.x; s_ty[j] = t.y; s_tz[j] = t.z; s_tw[j] = t.w;
        s_lab[j] = tlab[j];
    }
    // sigmoids for the tile's rows (same math as verified kernel)
    for (int u = threadIdx.x; u < TILE * CC; u += NTHREADS) {
        int r = u / CC, c = u % CC;
        float x = logits[((size_t)(b * QQ + r0 + r)) * CC + c];
        s_sig[r][c] = 1.0f / (1.0f + expf(-x));
    }
    // per-row box precompute
    if (threadIdx.x < TILE) {
        int r = threadIdx.x;
        const float4 p = *(const float4*)(pred + ((size_t)(b * QQ + r0 + r)) * 4);
        s_row[r][0] = p.x; s_row[r][1] = p.y; s_row[r][2] = p.z; s_row[r][3] = p.w;
        s_row[r][4] = p.x - 0.5f * p.z;
        s_row[r][5] = p.y - 0.5f * p.w;
        s_row[r][6] = p.x + 0.5f * p.z;
        s_row[r][7] = p.y + 0.5f * p.w;
    }
    __syncthreads();

    for (int r = 0; r < TILE; ++r) {
        const float px  = s_row[r][0], py  = s_row[r][1], pz  = s_row[r][2], pw  = s_row[r][3];
        const float p_x0 = s_row[r][4], p_y0 = s_row[r][5], p_x1 = s_row[r][6], p_y1 = s_row[r][7];
        const float area1 = (p_x1 - p_x0) * (p_y1 - p_y0);
        float* crow = cost + ((size_t)(b * QQ + r0 + r)) * BT;

        for (int j = threadIdx.x; j < BT; j += NTHREADS) {
            float tx = s_tx[j], ty = s_ty[j], tz = s_tz[j], tw = s_tw[j];
            float cclass = -s_sig[r][s_lab[j]];
            float cbbox = ((fabsf(px - tx) + fabsf(py - ty)) + fabsf(pz - tz)) + fabsf(pw - tw);

            float t_x0 = tx - 0.5f * tz, t_y0 = ty - 0.5f * tw;
            float t_x1 = tx + 0.5f * tz, t_y1 = ty + 0.5f * tw;
            float area2 = (t_x1 - t_x0) * (t_y1 - t_y0);

            float ltx = fmaxf(p_x0, t_x0), lty = fmaxf(p_y0, t_y0);
            float rbx = fminf(p_x1, t_x1), rby = fminf(p_y1, t_y1);
            float iw = fmaxf(rbx - ltx, 0.0f), ih = fmaxf(rby - lty, 0.0f);
            float inter = iw * ih;
            float uni = (area1 + area2) - inter;
            float iou = inter / uni;

            float ex0 = fminf(p_x0, t_x0), ey0 = fminf(p_y0, t_y0);
            float ex1 = fmaxf(p_x1, t_x1), ey1 = fmaxf(p_y1, t_y1);
            float ew = fmaxf(ex1 - ex0, 0.0f), eh = fmaxf(ey1 - ey0, 0.0f);
            float ae = ew * eh;
            float giou = iou - (ae - uni) / ae;

            float v = (cbbox + cclass) + (-giou);
            crow[j] = v;
            if (j < TT) s_cmin[r][j] = v;   // only iteration 0, tids 0..99
        }
    }
    __syncthreads();

    // block-level column minima over the tile's 15 rows -> global atomicMin
    if (threadIdx.x < TT) {
        const int c = threadIdx.x;
        unsigned long long best = ~0ULL;
        #pragma unroll
        for (int r = 0; r < TILE; ++r)
            best = u64min(best, packkrc(ordkey(s_cmin[r][c]), r0 + r, c));
        atomicMin(colmin + (size_t)b * WSCOLS + c, best);
    }
}

// ---------------------------------------------------------------------------
// Kernel 2: greedy matcher, serial phase only. Column minima arrive
// precomputed in the workspace (packed u64, bit-identical to the old phase-1
// scan). One 64-lane wave per image; rescans (rare) read cost from cache.
// ---------------------------------------------------------------------------
__global__ __launch_bounds__(64, 1) void greedy_kernel(
    const float* __restrict__ cost,
    const unsigned long long* __restrict__ colmin,
    float*       __restrict__ rows_out,
    float*       __restrict__ cols_out)
{
    const int b = blockIdx.x;
    const int lane = threadIdx.x;
    const float* cb = cost + (size_t)b * QQ * BT;

    unsigned long long cola = colmin[(size_t)b * WSCOLS + lane];
    unsigned long long colb = (lane < TT - 64)
                            ? colmin[(size_t)b * WSCOLS + 64 + lane] : ~0ULL;

    // row-validity: bits 0..13 always (r = i*64+lane <= 895); bit 14 only lanes 0..3
    unsigned rowok = (lane < 4) ? 0x7FFFu : 0x3FFFu;

    for (int step = 0; step < TT; ++step) {
        // ---- global argmin over 100 column minima ----
        unsigned long long m = u64min(cola, colb);
        #pragma unroll
        for (int off = 1; off < 64; off <<= 1)
            m = u64min(m, __shfl_xor(m, off, 64));

        const int rstar = (int)((m >> 11) & 0x3FF);
        const int cstar = (int)(m & 0x7FF);

        if (lane == 0) {
            rows_out[b * TT + step] = (float)rstar;
            cols_out[b * TT + step] = (float)cstar;
        }

        // remove matched column / row
        if (lane == cstar)        cola = ~0ULL;
        if (lane + 64 == cstar)   colb = ~0ULL;
        if (lane == (rstar & 63)) rowok &= ~(1u << (rstar >> 6));

        // ---- columns whose cached argmin row just died (rare) ----
        unsigned long long hitsA = __ballot((int)((cola >> 11) & 0x3FF) == rstar);
        unsigned long long hitsB = __ballot((int)((colb >> 11) & 0x3FF) == rstar);

        while (hitsA | hitsB) {
            int c;
            if (hitsA) { c = (int)__ffsll((unsigned long long)hitsA) - 1;      hitsA &= hitsA - 1; }
            else       { c = (int)__ffsll((unsigned long long)hitsB) - 1 + 64; hitsB &= hitsB - 1; }

            // cooperative rescan of column c (c is wave-uniform)
            unsigned long long best = ~0ULL;
            #pragma unroll
            for (int i = 0; i < NSLOT; ++i) {
                if ((rowok >> i) & 1u) {
                    const int r = i * 64 + lane;
                    float v = cb[(size_t)r * BT + c];
                    best = u64min(best, packkrc(ordkey(v), r, c));
                }
            }
            #pragma unroll
            for (int off = 1; off < 64; off <<= 1)
                best = u64min(best, __shfl_xor(best, off, 64));

            if (lane == c)      cola = best;
            if (lane + 64 == c) colb = best;
        }
    }
}

extern "C" void kernel_launch(void* const* d_in, const int* in_sizes, int n_in,
                              void* d_out, int out_size, void* d_ws, size_t ws_size,
                              hipStream_t stream) {
    const float* logits = (const float*)d_in[0];   // [16,900,91]
    const float* pred   = (const float*)d_in[1];   // [16,900,4]
    const int*   tlab   = (const int*)d_in[2];     // [16,100]
    const float* tbox   = (const float*)d_in[3];   // [16,100,4]

    float* out = (float*)d_out;
    float* cost = out;                              // 23,040,000
    float* rows = out + (size_t)BB * QQ * BT;       // 1600
    float* cols = rows + (size_t)BB * TT;           // 1600

    unsigned long long* colmin = (unsigned long long*)d_ws;   // 16*128*8 = 16 KB

    // 0xFF-fill == ~0ULL sentinels (graph-capture legal)
    hipMemsetAsync(d_ws, 0xFF, (size_t)BB * WSCOLS * sizeof(unsigned long long), stream);

    cost_kernel<<<BB * NBLK_PER_IMG, NTHREADS, 0, stream>>>(logits, pred, tlab, tbox, cost, colmin);
    greedy_kernel<<<BB, 64, 0, stream>>>(cost, colmin, rows, cols);
}

// Round 2
// 204.732 us; speedup vs baseline: 1.2886x; 1.1050x over previous
//
#include <hip/hip_runtime.h>
#include <math.h>

#define BB 16
#define QQ 900
#define CC 91
#define TT 100
#define BT (BB * TT)        // 1600
#define NTHREADS 256
#define TILE 15             // query rows per cost block (900 % 15 == 0)
#define NBLK_PER_IMG (QQ / TILE)   // 60
#define NSLOT 15            // ceil(900/64) row slots per lane
#define WSCOLS 128          // u64 workspace slots per image
#define PENDK 8             // pending-buffer slots (measured ~3 concurrent max)

__device__ __forceinline__ unsigned ordkey(float f) {
    unsigned u = __float_as_uint(f);
    return (u & 0x80000000u) ? ~u : (u | 0x80000000u);
}

__device__ __forceinline__ unsigned long long u64min(unsigned long long a, unsigned long long b) {
    return a < b ? a : b;
}
__device__ __forceinline__ unsigned long long u64max(unsigned long long a, unsigned long long b) {
    return a > b ? a : b;
}

// pack (key,row,col) -> u64; lexicographic == numpy flat-index argmin order
__device__ __forceinline__ unsigned long long packkrc(unsigned key, int row, int col) {
    return ((unsigned long long)key << 21) | ((unsigned long long)row << 11) | (unsigned)col;
}

__device__ __forceinline__ unsigned long long rdlane64(unsigned long long v, int l) {
    unsigned lo = (unsigned)__builtin_amdgcn_readlane((int)(unsigned)v, l);
    unsigned hi = (unsigned)__builtin_amdgcn_readlane((int)(unsigned)(v >> 32), l);
    return ((unsigned long long)hi << 32) | lo;
}

// ---------------------------------------------------------------------------
// Kernel 1: cost[b,q,j], tiled 15 rows/block, LDS-staged targets (SoA).
// Column minima (cols 0..99) accumulate in a register per thread (tid<100
// sees j==tid every row) and atomicMin into the packed-u64 workspace.
// Numerics: EXACT expression tree of the verified kernel.
// ---------------------------------------------------------------------------
__global__ __launch_bounds__(NTHREADS) void cost_kernel(
    const float* __restrict__ logits,
    const float* __restrict__ pred,
    const int*   __restrict__ tlab,
    const float* __restrict__ tbox,
    float*       __restrict__ cost,
    unsigned long long* __restrict__ colmin)
{
    const int b  = blockIdx.x / NBLK_PER_IMG;
    const int tb = blockIdx.x % NBLK_PER_IMG;
    const int r0 = tb * TILE;                 // first query row of this tile

    __shared__ float s_tx[BT], s_ty[BT], s_tz[BT], s_tw[BT];  // SoA targets
    __shared__ int   s_lab[BT];
    __shared__ float s_sig[TILE][CC];
    __shared__ float s_row[TILE][8];          // px,py,pz,pw,x0,y0,x1,y1

    for (int j = threadIdx.x; j < BT; j += NTHREADS) {
        float4 t = *(const float4*)(tbox + (size_t)j * 4);
        s_tx[j] = t.x; s_ty[j] = t.y; s_tz[j] = t.z; s_tw[j] = t.w;
        s_lab[j] = tlab[j];
    }
    for (int u = threadIdx.x; u < TILE * CC; u += NTHREADS) {
        int r = u / CC, c = u % CC;
        float x = logits[((size_t)(b * QQ + r0 + r)) * CC + c];
        s_sig[r][c] = 1.0f / (1.0f + expf(-x));
    }
    if (threadIdx.x < TILE) {
        int r = threadIdx.x;
        const float4 p = *(const float4*)(pred + ((size_t)(b * QQ + r0 + r)) * 4);
        s_row[r][0] = p.x; s_row[r][1] = p.y; s_row[r][2] = p.z; s_row[r][3] = p.w;
        s_row[r][4] = p.x - 0.5f * p.z;
        s_row[r][5] = p.y - 0.5f * p.w;
        s_row[r][6] = p.x + 0.5f * p.z;
        s_row[r][7] = p.y + 0.5f * p.w;
    }
    __syncthreads();

    unsigned long long bestc = ~0ULL;   // column-min for col==threadIdx.x (<100)

    for (int r = 0; r < TILE; ++r) {
        const float px  = s_row[r][0], py  = s_row[r][1], pz  = s_row[r][2], pw  = s_row[r][3];
        const float p_x0 = s_row[r][4], p_y0 = s_row[r][5], p_x1 = s_row[r][6], p_y1 = s_row[r][7];
        const float area1 = (p_x1 - p_x0) * (p_y1 - p_y0);
        float* crow = cost + ((size_t)(b * QQ + r0 + r)) * BT;

        for (int j = threadIdx.x; j < BT; j += NTHREADS) {
            float tx = s_tx[j], ty = s_ty[j], tz = s_tz[j], tw = s_tw[j];
            float cclass = -s_sig[r][s_lab[j]];
            float cbbox = ((fabsf(px - tx) + fabsf(py - ty)) + fabsf(pz - tz)) + fabsf(pw - tw);

            float t_x0 = tx - 0.5f * tz, t_y0 = ty - 0.5f * tw;
            float t_x1 = tx + 0.5f * tz, t_y1 = ty + 0.5f * tw;
            float area2 = (t_x1 - t_x0) * (t_y1 - t_y0);

            float ltx = fmaxf(p_x0, t_x0), lty = fmaxf(p_y0, t_y0);
            float rbx = fminf(p_x1, t_x1), rby = fminf(p_y1, t_y1);
            float iw = fmaxf(rbx - ltx, 0.0f), ih = fmaxf(rby - lty, 0.0f);
            float inter = iw * ih;
            float uni = (area1 + area2) - inter;
            float iou = inter / uni;

            float ex0 = fminf(p_x0, t_x0), ey0 = fminf(p_y0, t_y0);
            float ex1 = fmaxf(p_x1, t_x1), ey1 = fmaxf(p_y1, t_y1);
            float ew = fmaxf(ex1 - ex0, 0.0f), eh = fmaxf(ey1 - ey0, 0.0f);
            float ae = ew * eh;
            float giou = iou - (ae - uni) / ae;

            float v = (cbbox + cclass) + (-giou);
            crow[j] = v;
            if (j < TT) bestc = u64min(bestc, packkrc(ordkey(v), r0 + r, j));
        }
    }

    if (threadIdx.x < TT)
        atomicMin(colmin + (size_t)b * WSCOLS + threadIdx.x, bestc);
}

// ---------------------------------------------------------------------------
// Kernel 2: greedy matcher = lazy-deletion priority queue.
// Bitonic-sort the 100 (pad to 128) packed column minima ONCE (27 shuffle
// levels), then walk the sorted list with readlane (~150cy/step) instead of
// a 6-level u64 butterfly per step. Popped entries whose cached argmin row
// died get a cooperative column rescan and go to a wave-uniform pending
// buffer (rare: ~2.7/image measured). Ordering is bit-identical to the
// reference flat-scan argmin (packed (key,row,col) lexicographic).
// ---------------------------------------------------------------------------
__global__ __launch_bounds__(64, 1) void greedy_kernel(
    const float* __restrict__ cost,
    const unsigned long long* __restrict__ colmin,
    float*       __restrict__ rows_out,
    float*       __restrict__ cols_out)
{
    const int b = blockIdx.x;
    const int lane = threadIdx.x;
    const float* cb = cost + (size_t)b * QQ * BT;

    // ---- load 100 column minima; pad to 128 with ~0 ----
    unsigned long long va = colmin[(size_t)b * WSCOLS + lane];              // idx = lane
    unsigned long long vb = (lane < TT - 64)
                          ? colmin[(size_t)b * WSCOLS + 64 + lane] : ~0ULL; // idx = 64+lane

    // ---- bitonic sort, 128 elements across 64 lanes x 2 regs, ascending ----
    #pragma unroll
    for (int k = 2; k <= 128; k <<= 1) {
        #pragma unroll
        for (int j = k >> 1; j > 0; j >>= 1) {
            if (j == 64) {
                // in-lane: idx lane vs idx lane+64; k==128 -> ascending for all
                unsigned long long lo = u64min(va, vb);
                unsigned long long hi = va ^ vb ^ lo;
                va = lo; vb = hi;
            } else {
                unsigned long long pa = __shfl_xor(va, j, 64);
                bool ta = ((lane & j) == 0) == ((lane & k) == 0);
                va = ta ? u64min(va, pa) : u64max(va, pa);
                unsigned long long pb = __shfl_xor(vb, j, 64);
                int ib = lane + 64;
                bool tb_ = ((ib & j) == 0) == ((ib & k) == 0);
                vb = tb_ ? u64min(vb, pb) : u64max(vb, pb);
            }
        }
    }

    // ---- serial walk ----
    unsigned rowok = (lane < 4) ? 0x7FFFu : 0x3FFFu;   // 15-bit row-validity per lane
    unsigned long long pend[PENDK];
    #pragma unroll
    for (int t = 0; t < PENDK; ++t) pend[t] = ~0ULL;
    unsigned long long pmin = ~0ULL;

    int p = 0;   // next sorted index (wave-uniform)
    int match = 0;
    while (match < TT) {
        unsigned long long s = (p < 64) ? rdlane64(va, p)
                             : (p < 128) ? rdlane64(vb, p - 64) : ~0ULL;
        bool fromPend = pmin < s;
        unsigned long long e = fromPend ? pmin : s;

        const int rstar = (int)((e >> 11) & 0x3FF);
        const int cstar = (int)(e & 0x7FF);

        // row still alive?  (owner lane tests its validity bit)
        bool alive = __ballot((lane == (rstar & 63)) && ((rowok >> (rstar >> 6)) & 1u)) != 0ULL;

        if (fromPend) {
            bool removed = false;
            #pragma unroll
            for (int t = 0; t < PENDK; ++t) {
                if (!removed && pend[t] == e) { pend[t] = ~0ULL; removed = true; }
            }
            pmin = ~0ULL;
            #pragma unroll
            for (int t = 0; t < PENDK; ++t) pmin = u64min(pmin, pend[t]);
        } else {
            ++p;
        }

        if (alive) {
            if (lane == 0) {
                rows_out[b * TT + match] = (float)rstar;
                cols_out[b * TT + match] = (float)cstar;
            }
            if (lane == (rstar & 63)) rowok &= ~(1u << (rstar >> 6));
            ++match;
        } else {
            // cached argmin row died earlier: rescan column cstar (rare)
            unsigned long long best = ~0ULL;
            #pragma unroll
            for (int i = 0; i < NSLOT; ++i) {
                if ((rowok >> i) & 1u) {
                    const int r = i * 64 + lane;
                    float v = cb[(size_t)r * BT + cstar];
                    best = u64min(best, packkrc(ordkey(v), r, cstar));
                }
            }
            #pragma unroll
            for (int off = 1; off < 64; off <<= 1)
                best = u64min(best, __shfl_xor(best, off, 64));

            bool placed = false;
            #pragma unroll
            for (int t = 0; t < PENDK; ++t) {
                if (!placed && pend[t] == ~0ULL) { pend[t] = best; placed = true; }
            }
            pmin = u64min(pmin, best);
        }
    }
}

extern "C" void kernel_launch(void* const* d_in, const int* in_sizes, int n_in,
                              void* d_out, int out_size, void* d_ws, size_t ws_size,
                              hipStream_t stream) {
    const float* logits = (const float*)d_in[0];   // [16,900,91]
    const float* pred   = (const float*)d_in[1];   // [16,900,4]
    const int*   tlab   = (const int*)d_in[2];     // [16,100]
    const float* tbox   = (const float*)d_in[3];   // [16,100,4]

    float* out = (float*)d_out;
    float* cost = out;                              // 23,040,000
    float* rows = out + (size_t)BB * QQ * BT;       // 1600
    float* cols = rows + (size_t)BB * TT;           // 1600

    unsigned long long* colmin = (unsigned long long*)d_ws;   // 16*128*8 = 16 KB

    // 0xFF-fill == ~0ULL sentinels (graph-capture legal)
    hipMemsetAsync(d_ws, 0xFF, (size_t)BB * WSCOLS * sizeof(unsigned long long), stream);

    cost_kernel<<<BB * NBLK_PER_IMG, NTHREADS, 0, stream>>>(logits, pred, tlab, tbox, cost, colmin);
    greedy_kernel<<<BB, 64, 0, stream>>>(cost, colmin, rows, cols);
}